// Round 20
// baseline (115.536 us; speedup 1.0000x reference)
//
#include <hip/hip_runtime.h>
#include <hip/hip_bf16.h>

typedef short short8 __attribute__((ext_vector_type(8)));
typedef float f32x4 __attribute__((ext_vector_type(4)));

#define NB   2
#define SEQ  2048
#define CH   1024
#define NH   16
#define HD   64
#define MROWS (NB*SEQ)          // 4096
#define QSZ  (NB*NH*SEQ*HD)     // 4194304 elems per tensor
#define NX   ((size_t)MROWS * CH)        // 4,194,304
#define NWQ  ((size_t)3 * CH * CH)       // 3,145,728
#define NWP  ((size_t)CH * CH)           // 1,048,576

// Q pre-scale: 1/sqrt(64) * log2(e)  -> softmax computed in exp2 domain
#define QSCALE 0.1803368801111204f

// bare v_exp_f32 (base-2), no libm denormal fix-up path
#define EXP2(x) __builtin_amdgcn_exp2f(x)

struct DiagTag  { static constexpr bool value = true;  };
struct InnerTag { static constexpr bool value = false; };

__device__ __forceinline__ f32x4 mfma16(short8 a, short8 b, f32x4 c) {
    return __builtin_amdgcn_mfma_f32_16x16x32_bf16(a, b, c, 0, 0, 0);
}

__device__ __forceinline__ short bf16_of(float f) {
    return __builtin_bit_cast(short, __float2bfloat16(f));
}
__device__ __forceinline__ unsigned int pkbf(float a, float b) {
    return (unsigned int)(unsigned short)bf16_of(a)
         | ((unsigned int)(unsigned short)bf16_of(b) << 16);
}

__device__ __forceinline__ short8 load8(const __hip_bfloat16* p) {
    return *reinterpret_cast<const short8*>(p);
}
__device__ __forceinline__ short8 load8(const float* p) {
    f32x4 a = *reinterpret_cast<const f32x4*>(p);
    f32x4 b = *reinterpret_cast<const f32x4*>(p + 4);
    short8 r;
    r[0] = bf16_of(a[0]); r[1] = bf16_of(a[1]);
    r[2] = bf16_of(a[2]); r[3] = bf16_of(a[3]);
    r[4] = bf16_of(b[0]); r[5] = bf16_of(b[1]);
    r[6] = bf16_of(b[2]); r[7] = bf16_of(b[3]);
    return r;
}

// async global->LDS, 16 bytes per lane (lds dest = wave-uniform base + lane*16)
__device__ __forceinline__ void gload_lds16(const void* g, void* l) {
    __builtin_amdgcn_global_load_lds(
        (const __attribute__((address_space(1))) unsigned int*)g,
        (__attribute__((address_space(3))) unsigned int*)l, 16, 0, 0);
}

// ---------------------------------------------------------------------------
// fused fp32 -> bf16 convert into K-TILED layout: dst[(k>>5)][row][k&31].
// ---------------------------------------------------------------------------
__global__ void cvt3_kernel(const float* __restrict__ x,
                            const float* __restrict__ wq,
                            const float* __restrict__ wp,
                            __hip_bfloat16* __restrict__ xb,
                            __hip_bfloat16* __restrict__ wqb,
                            __hip_bfloat16* __restrict__ wpb) {
    const size_t i = ((size_t)blockIdx.x * 256 + threadIdx.x) * 8;
    const float* src;
    __hip_bfloat16* dst;
    if (i < NX) {
        const size_t m = i >> 10, k = i & 1023;
        src = x + i;
        dst = xb + (k >> 5) * ((size_t)MROWS * 32) + m * 32 + (k & 31);
    } else if (i < NX + NWQ) {
        const size_t j = i - NX;
        const size_t n = j >> 10, k = j & 1023;
        src = wq + j;
        dst = wqb + (k >> 5) * ((size_t)3072 * 32) + n * 32 + (k & 31);
    } else {
        const size_t j = i - NX - NWQ;
        const size_t n = j >> 10, k = j & 1023;
        src = wp + j;
        dst = wpb + (k >> 5) * ((size_t)1024 * 32) + n * 32 + (k & 31);
    }
    *(short8*)dst = load8(src);
}

// ---------------------------------------------------------------------------
// GEMM w8 (r13-verified): 128x128 tile, BK=32, K-tiled operands, gload_lds
// dbuf, 8 waves (512 thr), wave tile 64x32. EPI=0: fp32; EPI=1: qkv routing
// (q pre-scaled by QSCALE for exp2-domain softmax).
// ---------------------------------------------------------------------------
template<int EPI>
__global__ __launch_bounds__(512, 6)
void gemm_w8(const __hip_bfloat16* __restrict__ A,
             const __hip_bfloat16* __restrict__ W,
             int K, int N,
             float* __restrict__ Cout,
             __hip_bfloat16* __restrict__ qp,
             __hip_bfloat16* __restrict__ kp,
             __hip_bfloat16* __restrict__ vtp)
{
    __shared__ alignas(16) __hip_bfloat16 Asm[2][128 * 32];
    __shared__ alignas(16) __hip_bfloat16 Bsm[2][128 * 32];

    const int tid  = threadIdx.x;
    const int lane = tid & 63;
    const int wave = tid >> 6;            // 0..7
    const int wm   = wave >> 2, wn = wave & 3;
    const int l15  = lane & 15, lg = lane >> 4;
    const int m0   = blockIdx.x * 128;
    const int n0   = blockIdx.y * 128;

    f32x4 acc[4][2] = {};

    const int srow = lane >> 2;           // 0..15
    const int scol = (lane & 3) * 8;

    auto stage = [&](int buf, int k0) {
        const size_t ktA = (size_t)(k0 >> 5) * ((size_t)MROWS * 32);
        const size_t ktW = (size_t)(k0 >> 5) * ((size_t)N * 32);
        const int row = wave * 16;
        gload_lds16(A + ktA + (size_t)(m0 + row + srow) * 32 + scol,
                    &Asm[buf][row * 32]);
        gload_lds16(W + ktW + (size_t)(n0 + row + srow) * 32 + scol,
                    &Bsm[buf][row * 32]);
    };

    auto compute = [&](int buf) {
        short8 af[4], bfr[2];
        #pragma unroll
        for (int mi = 0; mi < 4; ++mi)
            af[mi] = *(const short8*)&Asm[buf][(wm * 64 + mi * 16 + l15) * 32 + lg * 8];
        #pragma unroll
        for (int ni = 0; ni < 2; ++ni)
            bfr[ni] = *(const short8*)&Bsm[buf][(wn * 32 + ni * 16 + l15) * 32 + lg * 8];
        #pragma unroll
        for (int mi = 0; mi < 4; ++mi)
            #pragma unroll
            for (int ni = 0; ni < 2; ++ni)
                acc[mi][ni] = mfma16(af[mi], bfr[ni], acc[mi][ni]);
    };

    stage(0, 0);
    int it = 0;
    for (int k0 = 0; k0 < K; k0 += 32, ++it) {
        const int cur = it & 1;
        __syncthreads();
        if (k0 + 32 < K) stage(cur ^ 1, k0 + 32);
        compute(cur);
    }

    #pragma unroll
    for (int mi = 0; mi < 4; ++mi) {
        #pragma unroll
        for (int ni = 0; ni < 2; ++ni) {
            #pragma unroll
            for (int j2 = 0; j2 < 4; ++j2) {
                const int m = m0 + wm * 64 + mi * 16 + lg * 4 + j2;
                const int n = n0 + wn * 32 + ni * 16 + l15;
                if constexpr (EPI == 0) {
                    Cout[(size_t)m * N + n] = acc[mi][ni][j2];
                } else {
                    const int sec = n >> 10;           // 0:q 1:k 2:v
                    const int c   = n & 1023;
                    const int h   = c >> 6, d = c & 63;
                    const int b   = m >> 11, s = m & 2047;
                    const int bh  = b * NH + h;
                    if (sec == 0) {
                        qp[((size_t)bh * SEQ + s) * HD + d] =
                            __float2bfloat16(acc[mi][ni][j2] * QSCALE);
                    } else if (sec == 1) {
                        kp[((size_t)bh * SEQ + s) * HD + d] =
                            __float2bfloat16(acc[mi][ni][j2]);
                    } else {
                        vtp[((size_t)bh * HD + d) * SEQ + s] =
                            __float2bfloat16(acc[mi][ni][j2]);
                    }
                }
            }
        }
    }
}

// ---------------------------------------------------------------------------
// legacy reg-staged GEMM (fallback path only, fp32-capable, row-major A/W)
// ---------------------------------------------------------------------------
template<int EPI, typename TA, typename TW>
__global__ __launch_bounds__(256, 2)
void gemm_bt(const TA* __restrict__ A,
             const TW* __restrict__ W,
             int K, int N,
             float* __restrict__ Cout,
             __hip_bfloat16* __restrict__ qp,
             __hip_bfloat16* __restrict__ kp,
             __hip_bfloat16* __restrict__ vtp)
{
    __shared__ alignas(16) __hip_bfloat16 Asm[128 * 32];
    __shared__ alignas(16) __hip_bfloat16 Bsm[128 * 32];

    const int tid  = threadIdx.x;
    const int lane = tid & 63;
    const int wave = tid >> 6;
    const int wm   = wave >> 1, wn = wave & 1;
    const int l15  = lane & 15, lg = lane >> 4;
    const int m0   = blockIdx.x * 128;
    const int n0   = blockIdx.y * 128;

    f32x4 acc[4][4] = {};

    const int c0 = tid, c1 = tid + 256;
    const int r0 = c0 >> 2, kc0 = (c0 & 3) << 3;
    const int r1 = c1 >> 2, kc1 = (c1 & 3) << 3;
    const TA* a0p = A + (size_t)(m0 + r0) * K + kc0;
    const TA* a1p = A + (size_t)(m0 + r1) * K + kc1;
    const TW* b0p = W + (size_t)(n0 + r0) * K + kc0;
    const TW* b1p = W + (size_t)(n0 + r1) * K + kc1;

    for (int k0 = 0; k0 < K; k0 += 32) {
        short8 av0 = load8(a0p + k0);
        short8 av1 = load8(a1p + k0);
        short8 bv0 = load8(b0p + k0);
        short8 bv1 = load8(b1p + k0);
        __syncthreads();
        *(short8*)&Asm[c0 * 8] = av0;
        *(short8*)&Asm[c1 * 8] = av1;
        *(short8*)&Bsm[c0 * 8] = bv0;
        *(short8*)&Bsm[c1 * 8] = bv1;
        __syncthreads();

        short8 af[4], bfr[4];
        #pragma unroll
        for (int mi = 0; mi < 4; ++mi)
            af[mi] = *(const short8*)&Asm[(wm * 64 + mi * 16 + l15) * 32 + lg * 8];
        #pragma unroll
        for (int ni = 0; ni < 4; ++ni)
            bfr[ni] = *(const short8*)&Bsm[(wn * 64 + ni * 16 + l15) * 32 + lg * 8];
        #pragma unroll
        for (int mi = 0; mi < 4; ++mi)
            #pragma unroll
            for (int ni = 0; ni < 4; ++ni)
                acc[mi][ni] = mfma16(af[mi], bfr[ni], acc[mi][ni]);
    }

    #pragma unroll
    for (int mi = 0; mi < 4; ++mi) {
        #pragma unroll
        for (int ni = 0; ni < 4; ++ni) {
            #pragma unroll
            for (int j = 0; j < 4; ++j) {
                const int m = m0 + wm * 64 + mi * 16 + lg * 4 + j;
                const int n = n0 + wn * 64 + ni * 16 + l15;
                if constexpr (EPI == 0) {
                    Cout[(size_t)m * N + n] = acc[mi][ni][j];
                } else {
                    const int sec = n >> 10;
                    const int c   = n & 1023;
                    const int h   = c >> 6, d = c & 63;
                    const int b   = m >> 11, s = m & 2047;
                    const int bh  = b * NH + h;
                    if (sec == 0) {
                        qp[((size_t)bh * SEQ + s) * HD + d] =
                            __float2bfloat16(acc[mi][ni][j] * QSCALE);
                    } else if (sec == 1) {
                        kp[((size_t)bh * SEQ + s) * HD + d] =
                            __float2bfloat16(acc[mi][ni][j]);
                    } else {
                        vtp[((size_t)bh * HD + d) * SEQ + s] =
                            __float2bfloat16(acc[mi][ni][j]);
                    }
                }
            }
        }
    }
}

// ---------------------------------------------------------------------------
// Flash attention v14 (causal). r19-verified v13 core (4 waves, 64-row Q
// chunks, K/V gload_lds dbuf, swapped QK^T in-register softmax, exp2 via
// bare v_exp_f32, XOR-swz P-bounce, 40960B LDS = 4 blocks/CU, XCD-grouped
// bh, heavy-first). Two critical-path trims:
//  - diagonal tile peeled out of the K-loop; inner tiles compile without
//    the 16 mask compare/selects (DIAG is a compile-time tag).
//  - V-fragment ds_reads hoisted before the softmax section so their
//    latency hides under the mask/max/exp VALU work.
// TILED=1: y written K-tiled for the proj GEMM.
// ---------------------------------------------------------------------------
template<int TILED>
__global__ __launch_bounds__(256, 4)
void attn_fwd14(const __hip_bfloat16* __restrict__ qp,
                const __hip_bfloat16* __restrict__ kp,
                const __hip_bfloat16* __restrict__ vtp,
                __hip_bfloat16* __restrict__ yp)
{
    __shared__ alignas(16) __hip_bfloat16 Ksm[2][64 * 64];
    __shared__ alignas(16) __hip_bfloat16 Vsm[2][64 * 64];
    __shared__ alignas(16) unsigned int Pw[4][16 * 32];   // packed bf16x2, XOR-swz

    const int tid  = threadIdx.x;
    const int lane = tid & 63, wave = tid >> 6;
    const int l15  = lane & 15, lg = lane >> 4;
    const int id   = blockIdx.x;
    // XCD-grouped: xcd = id%8 handles bh in [xcd*4, xcd*4+4); heavy chunks first
    const int xcd  = id & 7, rest = id >> 3;
    const int bh   = xcd * 4 + (rest & 3);
    const int c    = 31 - (rest >> 2);
    const int b    = bh >> 4, h = bh & 15;
    const int q0   = c * 64 + wave * 16;

    const __hip_bfloat16* Q  = qp  + (size_t)bh * SEQ * HD;
    const __hip_bfloat16* Kp = kp  + (size_t)bh * SEQ * HD;
    const __hip_bfloat16* Vt = vtp + (size_t)bh * HD * SEQ;

    short8 qf[2];
    #pragma unroll
    for (int dk = 0; dk < 2; ++dk)
        qf[dk] = *(const short8*)&Q[(size_t)(q0 + l15) * HD + dk * 32 + lg * 8];

    const short ONE = 0x3F80;   // bf16 1.0
    short8 ones;
    #pragma unroll
    for (int i = 0; i < 8; ++i) ones[i] = ONE;

    f32x4 o[4] = {};
    f32x4 accl = {};
    float m_r = -1e30f;          // running max (log2 domain) of q-row l15

    const int xorv = (l15 & 7) << 2;   // Pw bank swizzle (bits 2-4 only)

    auto stage = [&](int buf, int t) {
        const int kv0 = t * 64;
        #pragma unroll
        for (int j = 0; j < 2; ++j) {
            const int ch  = j * 256 + tid;
            const int row = ch >> 3, cb = ch & 7;
            const int cbs = cb ^ (row & 7);         // pre-swizzled source block
            gload_lds16(Kp + (size_t)(kv0 + row) * HD + cbs * 8,
                        &Ksm[buf][(j * 256 + wave * 64) * 8]);
            gload_lds16(Vt + (size_t)row * SEQ + kv0 + cbs * 8,
                        &Vsm[buf][(j * 256 + wave * 64) * 8]);
        }
    };

    auto computeT = [&](int buf, int t, auto diagtag) {
        constexpr bool DIAG = decltype(diagtag)::value;
        const int kv0 = t * 64;
        // S^T = K Q^T : C col(l15) = q-row, C row(lg*4+j) = k-col
        f32x4 s[4] = {};
        #pragma unroll
        for (int kf = 0; kf < 4; ++kf)
            #pragma unroll
            for (int dk = 0; dk < 2; ++dk) {
                short8 kfrag = *(const short8*)
                    &Ksm[buf][(kf * 16 + l15) * 64 + (((dk * 4 + lg) ^ (l15 & 7)) * 8)];
                s[kf] = mfma16(kfrag, qf[dk], s[kf]);
            }

        // hoist V-fragment ds_reads: latency hides under softmax VALU below
        short8 vf[4][2];
        #pragma unroll
        for (int dt = 0; dt < 4; ++dt) {
            vf[dt][0] = *(const short8*)
                &Vsm[buf][(dt * 16 + l15) * 64 + (((0 + lg) ^ (l15 & 7)) * 8)];
            vf[dt][1] = *(const short8*)
                &Vsm[buf][(dt * 16 + l15) * 64 + (((4 + lg) ^ (l15 & 7)) * 8)];
        }

        // mask (diag tile only, compile-time) + in-lane row max
        float v[4][4];
        const int qrow = q0 + l15;
        #pragma unroll
        for (int kf = 0; kf < 4; ++kf)
            #pragma unroll
            for (int j = 0; j < 4; ++j) {
                float sv = s[kf][j];
                if constexpr (DIAG) {
                    if (kv0 + kf * 16 + lg * 4 + j > qrow) sv = -1e30f;
                }
                v[kf][j] = sv;
            }
        float mxv = v[0][0];
        #pragma unroll
        for (int kf = 0; kf < 4; ++kf)
            #pragma unroll
            for (int j = 0; j < 4; ++j)
                mxv = fmaxf(mxv, v[kf][j]);
        mxv = fmaxf(mxv, __shfl_xor(mxv, 16));
        mxv = fmaxf(mxv, __shfl_xor(mxv, 32));   // row max over 64-k tile

        // defer-max (T13, exp2 domain): bound 2^11.5 ~ e^8
        if (__any(mxv > m_r + 11.5f)) {
            const float mn = fmaxf(m_r, mxv);
            const float r  = EXP2(m_r - mn);
            m_r = mn;
            float rj[4];
            #pragma unroll
            for (int j = 0; j < 4; ++j)
                rj[j] = __shfl(r, lg * 4 + j);
            #pragma unroll
            for (int j = 0; j < 4; ++j) {
                accl[j] *= rj[j];
                #pragma unroll
                for (int dt = 0; dt < 4; ++dt) o[dt][j] *= rj[j];
            }
        }

        // exp2 in-lane (bare v_exp_f32)
        #pragma unroll
        for (int kf = 0; kf < 4; ++kf)
            #pragma unroll
            for (int j = 0; j < 4; ++j)
                v[kf][j] = EXP2(v[kf][j] - m_r);

        // pack to bf16x2 words, bounce through wave-private XOR-swz LDS tile.
        unsigned int* myP = &Pw[wave][0];
        #pragma unroll
        for (int kf = 0; kf < 4; ++kf) {
            const int wbase = (l15 * 32 + lg * 2 + kf * 8) ^ xorv;  // even
            myP[wbase]     = pkbf(v[kf][0], v[kf][1]);
            myP[wbase + 1] = pkbf(v[kf][2], v[kf][3]);
        }
        asm volatile("s_waitcnt lgkmcnt(0)" ::: "memory");
        __builtin_amdgcn_sched_barrier(0);
        const int rbase = (l15 * 32 + lg * 4) ^ xorv;   // 16B-aligned
        short8 pa0 = *(const short8*)&Pw[wave][rbase];
        short8 pa1 = *(const short8*)&Pw[wave][rbase ^ 16];

        // row-sum via ones-MFMA (lands in O-layout) + PV
        accl = mfma16(pa0, ones, accl);
        accl = mfma16(pa1, ones, accl);
        #pragma unroll
        for (int dt = 0; dt < 4; ++dt) {
            o[dt] = mfma16(pa0, vf[dt][0], o[dt]);
            o[dt] = mfma16(pa1, vf[dt][1], o[dt]);
        }
    };

    stage(0, 0);
    for (int t = 0; t < c; ++t) {            // inner tiles: no mask code
        const int cur = t & 1;
        __syncthreads();
        stage(cur ^ 1, t + 1);
        computeT(cur, t, InnerTag{});
    }
    __syncthreads();                          // diagonal tile (peeled)
    computeT(c & 1, c, DiagTag{});

    // epilogue: O C-layout row(lg*4+j)=q-row, col(l15)=d.
    #pragma unroll
    for (int j = 0; j < 4; ++j) {
        const float inv_l = 1.0f / accl[j];
        const int s = q0 + lg * 4 + j;
        const int m = b * SEQ + s;
        #pragma unroll
        for (int dt = 0; dt < 4; ++dt) {
            const int col = h * 64 + dt * 16 + l15;
            const __hip_bfloat16 hv = __float2bfloat16(o[dt][j] * inv_l);
            if constexpr (TILED) {
                yp[(size_t)(col >> 5) * ((size_t)MROWS * 32)
                   + (size_t)m * 32 + (col & 31)] = hv;
            } else {
                yp[(size_t)m * CH + col] = hv;
            }
        }
    }
}

// ---------------------------------------------------------------------------
extern "C" void kernel_launch(void* const* d_in, const int* in_sizes, int n_in,
                              void* d_out, int out_size, void* d_ws, size_t ws_size,
                              hipStream_t stream)
{
    const float* x      = (const float*)d_in[0];
    const float* w_qkv  = (const float*)d_in[1];
    const float* w_proj = (const float*)d_in[2];
    float* out = (float*)d_out;

    __hip_bfloat16* ws = (__hip_bfloat16*)d_ws;

    if (ws_size >= 41943040ull) {
        __hip_bfloat16* xb   = ws;                     // K-tiled; dies after gemm1
        __hip_bfloat16* wqb  = ws + NX;                // K-tiled
        __hip_bfloat16* wpb  = ws + NX + NWQ;          // K-tiled
        __hip_bfloat16* q_ws = ws + NX + NWQ + NWP;
        __hip_bfloat16* k_ws = q_ws + (size_t)QSZ;
        __hip_bfloat16* vt_ws= k_ws + (size_t)QSZ;
        __hip_bfloat16* y_ws = xb;                     // K-tiled y (reuse xb slot)

        cvt3_kernel<<<(NX + NWQ + NWP) / 2048, 256, 0, stream>>>(
            x, w_qkv, w_proj, xb, wqb, wpb);

        gemm_w8<1><<<dim3(MROWS / 128, 3072 / 128), 512, 0, stream>>>(
            xb, wqb, CH, 3 * CH, nullptr, q_ws, k_ws, vt_ws);

        attn_fwd14<1><<<1024, 256, 0, stream>>>(q_ws, k_ws, vt_ws, y_ws);

        gemm_w8<0><<<dim3(MROWS / 128, CH / 128), 512, 0, stream>>>(
            y_ws, wpb, CH, CH, out, nullptr, nullptr, nullptr);
    } else {
        __hip_bfloat16* q_ws  = ws;
        __hip_bfloat16* k_ws  = ws + (size_t)QSZ;
        __hip_bfloat16* vt_ws = ws + (size_t)2 * QSZ;
        __hip_bfloat16* y_ws  = ws + (size_t)3 * QSZ;

        gemm_bt<1, float, float><<<dim3(MROWS / 128, 3072 / 128), 256, 0, stream>>>(
            x, w_qkv, CH, 3 * CH, nullptr, q_ws, k_ws, vt_ws);

        attn_fwd14<0><<<1024, 256, 0, stream>>>(q_ws, k_ws, vt_ws, y_ws);

        gemm_bt<0, __hip_bfloat16, float><<<dim3(MROWS / 128, CH / 128), 256, 0, stream>>>(
            y_ws, w_proj, CH, CH, out, nullptr, nullptr, nullptr);
    }
}

// Round 21
// 113.362 us; speedup vs baseline: 1.0192x; 1.0192x over previous
//
#include <hip/hip_runtime.h>
#include <hip/hip_bf16.h>

typedef short short8 __attribute__((ext_vector_type(8)));
typedef float f32x4 __attribute__((ext_vector_type(4)));

#define NB   2
#define SEQ  2048
#define CH   1024
#define NH   16
#define HD   64
#define MROWS (NB*SEQ)          // 4096
#define QSZ  (NB*NH*SEQ*HD)     // 4194304 elems per tensor
#define NX   ((size_t)MROWS * CH)        // 4,194,304
#define NWQ  ((size_t)3 * CH * CH)       // 3,145,728
#define NWP  ((size_t)CH * CH)           // 1,048,576

// Q pre-scale: 1/sqrt(64) * log2(e)  -> softmax computed in exp2 domain
#define QSCALE 0.1803368801111204f

// bare v_exp_f32 (base-2), no libm denormal fix-up path
#define EXP2(x) __builtin_amdgcn_exp2f(x)

__device__ __forceinline__ f32x4 mfma16(short8 a, short8 b, f32x4 c) {
    return __builtin_amdgcn_mfma_f32_16x16x32_bf16(a, b, c, 0, 0, 0);
}

__device__ __forceinline__ short bf16_of(float f) {
    return __builtin_bit_cast(short, __float2bfloat16(f));
}
__device__ __forceinline__ unsigned int pkbf(float a, float b) {
    return (unsigned int)(unsigned short)bf16_of(a)
         | ((unsigned int)(unsigned short)bf16_of(b) << 16);
}

__device__ __forceinline__ short8 load8(const __hip_bfloat16* p) {
    return *reinterpret_cast<const short8*>(p);
}
__device__ __forceinline__ short8 load8(const float* p) {
    f32x4 a = *reinterpret_cast<const f32x4*>(p);
    f32x4 b = *reinterpret_cast<const f32x4*>(p + 4);
    short8 r;
    r[0] = bf16_of(a[0]); r[1] = bf16_of(a[1]);
    r[2] = bf16_of(a[2]); r[3] = bf16_of(a[3]);
    r[4] = bf16_of(b[0]); r[5] = bf16_of(b[1]);
    r[6] = bf16_of(b[2]); r[7] = bf16_of(b[3]);
    return r;
}

// async global->LDS, 16 bytes per lane (lds dest = wave-uniform base + lane*16)
__device__ __forceinline__ void gload_lds16(const void* g, void* l) {
    __builtin_amdgcn_global_load_lds(
        (const __attribute__((address_space(1))) unsigned int*)g,
        (__attribute__((address_space(3))) unsigned int*)l, 16, 0, 0);
}

// ---------------------------------------------------------------------------
// fused fp32 -> bf16 convert into K-TILED layout: dst[(k>>5)][row][k&31].
// ---------------------------------------------------------------------------
__global__ void cvt3_kernel(const float* __restrict__ x,
                            const float* __restrict__ wq,
                            const float* __restrict__ wp,
                            __hip_bfloat16* __restrict__ xb,
                            __hip_bfloat16* __restrict__ wqb,
                            __hip_bfloat16* __restrict__ wpb) {
    const size_t i = ((size_t)blockIdx.x * 256 + threadIdx.x) * 8;
    const float* src;
    __hip_bfloat16* dst;
    if (i < NX) {
        const size_t m = i >> 10, k = i & 1023;
        src = x + i;
        dst = xb + (k >> 5) * ((size_t)MROWS * 32) + m * 32 + (k & 31);
    } else if (i < NX + NWQ) {
        const size_t j = i - NX;
        const size_t n = j >> 10, k = j & 1023;
        src = wq + j;
        dst = wqb + (k >> 5) * ((size_t)3072 * 32) + n * 32 + (k & 31);
    } else {
        const size_t j = i - NX - NWQ;
        const size_t n = j >> 10, k = j & 1023;
        src = wp + j;
        dst = wpb + (k >> 5) * ((size_t)1024 * 32) + n * 32 + (k & 31);
    }
    *(short8*)dst = load8(src);
}

// ---------------------------------------------------------------------------
// GEMM w8 (r13-verified): 128x128 tile, BK=32, K-tiled operands, gload_lds
// dbuf, 8 waves (512 thr), wave tile 64x32. EPI=0: fp32; EPI=1: qkv routing
// (q pre-scaled by QSCALE for exp2-domain softmax).
// ---------------------------------------------------------------------------
template<int EPI>
__global__ __launch_bounds__(512, 6)
void gemm_w8(const __hip_bfloat16* __restrict__ A,
             const __hip_bfloat16* __restrict__ W,
             int K, int N,
             float* __restrict__ Cout,
             __hip_bfloat16* __restrict__ qp,
             __hip_bfloat16* __restrict__ kp,
             __hip_bfloat16* __restrict__ vtp)
{
    __shared__ alignas(16) __hip_bfloat16 Asm[2][128 * 32];
    __shared__ alignas(16) __hip_bfloat16 Bsm[2][128 * 32];

    const int tid  = threadIdx.x;
    const int lane = tid & 63;
    const int wave = tid >> 6;            // 0..7
    const int wm   = wave >> 2, wn = wave & 3;
    const int l15  = lane & 15, lg = lane >> 4;
    const int m0   = blockIdx.x * 128;
    const int n0   = blockIdx.y * 128;

    f32x4 acc[4][2] = {};

    const int srow = lane >> 2;           // 0..15
    const int scol = (lane & 3) * 8;

    auto stage = [&](int buf, int k0) {
        const size_t ktA = (size_t)(k0 >> 5) * ((size_t)MROWS * 32);
        const size_t ktW = (size_t)(k0 >> 5) * ((size_t)N * 32);
        const int row = wave * 16;
        gload_lds16(A + ktA + (size_t)(m0 + row + srow) * 32 + scol,
                    &Asm[buf][row * 32]);
        gload_lds16(W + ktW + (size_t)(n0 + row + srow) * 32 + scol,
                    &Bsm[buf][row * 32]);
    };

    auto compute = [&](int buf) {
        short8 af[4], bfr[2];
        #pragma unroll
        for (int mi = 0; mi < 4; ++mi)
            af[mi] = *(const short8*)&Asm[buf][(wm * 64 + mi * 16 + l15) * 32 + lg * 8];
        #pragma unroll
        for (int ni = 0; ni < 2; ++ni)
            bfr[ni] = *(const short8*)&Bsm[buf][(wn * 32 + ni * 16 + l15) * 32 + lg * 8];
        #pragma unroll
        for (int mi = 0; mi < 4; ++mi)
            #pragma unroll
            for (int ni = 0; ni < 2; ++ni)
                acc[mi][ni] = mfma16(af[mi], bfr[ni], acc[mi][ni]);
    };

    stage(0, 0);
    int it = 0;
    for (int k0 = 0; k0 < K; k0 += 32, ++it) {
        const int cur = it & 1;
        __syncthreads();
        if (k0 + 32 < K) stage(cur ^ 1, k0 + 32);
        compute(cur);
    }

    #pragma unroll
    for (int mi = 0; mi < 4; ++mi) {
        #pragma unroll
        for (int ni = 0; ni < 2; ++ni) {
            #pragma unroll
            for (int j2 = 0; j2 < 4; ++j2) {
                const int m = m0 + wm * 64 + mi * 16 + lg * 4 + j2;
                const int n = n0 + wn * 32 + ni * 16 + l15;
                if constexpr (EPI == 0) {
                    Cout[(size_t)m * N + n] = acc[mi][ni][j2];
                } else {
                    const int sec = n >> 10;           // 0:q 1:k 2:v
                    const int c   = n & 1023;
                    const int h   = c >> 6, d = c & 63;
                    const int b   = m >> 11, s = m & 2047;
                    const int bh  = b * NH + h;
                    if (sec == 0) {
                        qp[((size_t)bh * SEQ + s) * HD + d] =
                            __float2bfloat16(acc[mi][ni][j2] * QSCALE);
                    } else if (sec == 1) {
                        kp[((size_t)bh * SEQ + s) * HD + d] =
                            __float2bfloat16(acc[mi][ni][j2]);
                    } else {
                        vtp[((size_t)bh * HD + d) * SEQ + s] =
                            __float2bfloat16(acc[mi][ni][j2]);
                    }
                }
            }
        }
    }
}

// ---------------------------------------------------------------------------
// legacy reg-staged GEMM (fallback path only, fp32-capable, row-major A/W)
// ---------------------------------------------------------------------------
template<int EPI, typename TA, typename TW>
__global__ __launch_bounds__(256, 2)
void gemm_bt(const TA* __restrict__ A,
             const TW* __restrict__ W,
             int K, int N,
             float* __restrict__ Cout,
             __hip_bfloat16* __restrict__ qp,
             __hip_bfloat16* __restrict__ kp,
             __hip_bfloat16* __restrict__ vtp)
{
    __shared__ alignas(16) __hip_bfloat16 Asm[128 * 32];
    __shared__ alignas(16) __hip_bfloat16 Bsm[128 * 32];

    const int tid  = threadIdx.x;
    const int lane = tid & 63;
    const int wave = tid >> 6;
    const int wm   = wave >> 1, wn = wave & 1;
    const int l15  = lane & 15, lg = lane >> 4;
    const int m0   = blockIdx.x * 128;
    const int n0   = blockIdx.y * 128;

    f32x4 acc[4][4] = {};

    const int c0 = tid, c1 = tid + 256;
    const int r0 = c0 >> 2, kc0 = (c0 & 3) << 3;
    const int r1 = c1 >> 2, kc1 = (c1 & 3) << 3;
    const TA* a0p = A + (size_t)(m0 + r0) * K + kc0;
    const TA* a1p = A + (size_t)(m0 + r1) * K + kc1;
    const TW* b0p = W + (size_t)(n0 + r0) * K + kc0;
    const TW* b1p = W + (size_t)(n0 + r1) * K + kc1;

    for (int k0 = 0; k0 < K; k0 += 32) {
        short8 av0 = load8(a0p + k0);
        short8 av1 = load8(a1p + k0);
        short8 bv0 = load8(b0p + k0);
        short8 bv1 = load8(b1p + k0);
        __syncthreads();
        *(short8*)&Asm[c0 * 8] = av0;
        *(short8*)&Asm[c1 * 8] = av1;
        *(short8*)&Bsm[c0 * 8] = bv0;
        *(short8*)&Bsm[c1 * 8] = bv1;
        __syncthreads();

        short8 af[4], bfr[4];
        #pragma unroll
        for (int mi = 0; mi < 4; ++mi)
            af[mi] = *(const short8*)&Asm[(wm * 64 + mi * 16 + l15) * 32 + lg * 8];
        #pragma unroll
        for (int ni = 0; ni < 4; ++ni)
            bfr[ni] = *(const short8*)&Bsm[(wn * 64 + ni * 16 + l15) * 32 + lg * 8];
        #pragma unroll
        for (int mi = 0; mi < 4; ++mi)
            #pragma unroll
            for (int ni = 0; ni < 4; ++ni)
                acc[mi][ni] = mfma16(af[mi], bfr[ni], acc[mi][ni]);
    }

    #pragma unroll
    for (int mi = 0; mi < 4; ++mi) {
        #pragma unroll
        for (int ni = 0; ni < 4; ++ni) {
            #pragma unroll
            for (int j = 0; j < 4; ++j) {
                const int m = m0 + wm * 64 + mi * 16 + lg * 4 + j;
                const int n = n0 + wn * 64 + ni * 16 + l15;
                if constexpr (EPI == 0) {
                    Cout[(size_t)m * N + n] = acc[mi][ni][j];
                } else {
                    const int sec = n >> 10;
                    const int c   = n & 1023;
                    const int h   = c >> 6, d = c & 63;
                    const int b   = m >> 11, s = m & 2047;
                    const int bh  = b * NH + h;
                    if (sec == 0) {
                        qp[((size_t)bh * SEQ + s) * HD + d] =
                            __float2bfloat16(acc[mi][ni][j] * QSCALE);
                    } else if (sec == 1) {
                        kp[((size_t)bh * SEQ + s) * HD + d] =
                            __float2bfloat16(acc[mi][ni][j]);
                    } else {
                        vtp[((size_t)bh * HD + d) * SEQ + s] =
                            __float2bfloat16(acc[mi][ni][j]);
                    }
                }
            }
        }
    }
}

// ---------------------------------------------------------------------------
// Flash attention v13 (causal; r19-verified best, 44.7us). 4 waves, 64-row
// Q chunks, K/V gload_lds dbuf, swapped QK^T in-register softmax, exp2 via
// bare v_exp_f32, XOR-swizzled P-bounce (40960B LDS = 4 blocks/CU, 1024
// blocks all co-resident), XCD-grouped bh, heavy-first.
// TILED=1: y written K-tiled for the proj GEMM.
// ---------------------------------------------------------------------------
template<int TILED>
__global__ __launch_bounds__(256, 4)
void attn_fwd13(const __hip_bfloat16* __restrict__ qp,
                const __hip_bfloat16* __restrict__ kp,
                const __hip_bfloat16* __restrict__ vtp,
                __hip_bfloat16* __restrict__ yp)
{
    __shared__ alignas(16) __hip_bfloat16 Ksm[2][64 * 64];
    __shared__ alignas(16) __hip_bfloat16 Vsm[2][64 * 64];
    __shared__ alignas(16) unsigned int Pw[4][16 * 32];   // packed bf16x2, XOR-swz

    const int tid  = threadIdx.x;
    const int lane = tid & 63, wave = tid >> 6;
    const int l15  = lane & 15, lg = lane >> 4;
    const int id   = blockIdx.x;
    // XCD-grouped: xcd = id%8 handles bh in [xcd*4, xcd*4+4); heavy chunks first
    const int xcd  = id & 7, rest = id >> 3;
    const int bh   = xcd * 4 + (rest & 3);
    const int c    = 31 - (rest >> 2);
    const int b    = bh >> 4, h = bh & 15;
    const int q0   = c * 64 + wave * 16;

    const __hip_bfloat16* Q  = qp  + (size_t)bh * SEQ * HD;
    const __hip_bfloat16* Kp = kp  + (size_t)bh * SEQ * HD;
    const __hip_bfloat16* Vt = vtp + (size_t)bh * HD * SEQ;

    short8 qf[2];
    #pragma unroll
    for (int dk = 0; dk < 2; ++dk)
        qf[dk] = *(const short8*)&Q[(size_t)(q0 + l15) * HD + dk * 32 + lg * 8];

    const short ONE = 0x3F80;   // bf16 1.0
    short8 ones;
    #pragma unroll
    for (int i = 0; i < 8; ++i) ones[i] = ONE;

    f32x4 o[4] = {};
    f32x4 accl = {};
    float m_r = -1e30f;          // running max (log2 domain) of q-row l15

    const int xorv = (l15 & 7) << 2;   // Pw bank swizzle (bits 2-4 only)

    auto stage = [&](int buf, int t) {
        const int kv0 = t * 64;
        #pragma unroll
        for (int j = 0; j < 2; ++j) {
            const int ch  = j * 256 + tid;
            const int row = ch >> 3, cb = ch & 7;
            const int cbs = cb ^ (row & 7);         // pre-swizzled source block
            gload_lds16(Kp + (size_t)(kv0 + row) * HD + cbs * 8,
                        &Ksm[buf][(j * 256 + wave * 64) * 8]);
            gload_lds16(Vt + (size_t)row * SEQ + kv0 + cbs * 8,
                        &Vsm[buf][(j * 256 + wave * 64) * 8]);
        }
    };

    auto compute = [&](int buf, int t) {
        const int kv0 = t * 64;
        // S^T = K Q^T : C col(l15) = q-row, C row(lg*4+j) = k-col
        f32x4 s[4] = {};
        #pragma unroll
        for (int kf = 0; kf < 4; ++kf)
            #pragma unroll
            for (int dk = 0; dk < 2; ++dk) {
                short8 kfrag = *(const short8*)
                    &Ksm[buf][(kf * 16 + l15) * 64 + (((dk * 4 + lg) ^ (l15 & 7)) * 8)];
                s[kf] = mfma16(kfrag, qf[dk], s[kf]);
            }

        // mask (diag tile only) + in-lane row max
        float v[4][4];
        const bool diag = (t == c);
        const int qrow = q0 + l15;
        #pragma unroll
        for (int kf = 0; kf < 4; ++kf)
            #pragma unroll
            for (int j = 0; j < 4; ++j) {
                float sv = s[kf][j];
                if (diag && (kv0 + kf * 16 + lg * 4 + j > qrow)) sv = -1e30f;
                v[kf][j] = sv;
            }
        float mxv = v[0][0];
        #pragma unroll
        for (int kf = 0; kf < 4; ++kf)
            #pragma unroll
            for (int j = 0; j < 4; ++j)
                mxv = fmaxf(mxv, v[kf][j]);
        mxv = fmaxf(mxv, __shfl_xor(mxv, 16));
        mxv = fmaxf(mxv, __shfl_xor(mxv, 32));   // row max over 64-k tile

        // defer-max (T13, exp2 domain): bound 2^11.5 ~ e^8
        if (__any(mxv > m_r + 11.5f)) {
            const float mn = fmaxf(m_r, mxv);
            const float r  = EXP2(m_r - mn);
            m_r = mn;
            float rj[4];
            #pragma unroll
            for (int j = 0; j < 4; ++j)
                rj[j] = __shfl(r, lg * 4 + j);
            #pragma unroll
            for (int j = 0; j < 4; ++j) {
                accl[j] *= rj[j];
                #pragma unroll
                for (int dt = 0; dt < 4; ++dt) o[dt][j] *= rj[j];
            }
        }

        // exp2 in-lane (bare v_exp_f32)
        #pragma unroll
        for (int kf = 0; kf < 4; ++kf)
            #pragma unroll
            for (int j = 0; j < 4; ++j)
                v[kf][j] = EXP2(v[kf][j] - m_r);

        // pack to bf16x2 words, bounce through wave-private XOR-swz LDS tile.
        unsigned int* myP = &Pw[wave][0];
        #pragma unroll
        for (int kf = 0; kf < 4; ++kf) {
            const int wbase = (l15 * 32 + lg * 2 + kf * 8) ^ xorv;  // even
            myP[wbase]     = pkbf(v[kf][0], v[kf][1]);
            myP[wbase + 1] = pkbf(v[kf][2], v[kf][3]);
        }
        asm volatile("s_waitcnt lgkmcnt(0)" ::: "memory");
        __builtin_amdgcn_sched_barrier(0);
        const int rbase = (l15 * 32 + lg * 4) ^ xorv;   // 16B-aligned
        short8 pa0 = *(const short8*)&Pw[wave][rbase];
        short8 pa1 = *(const short8*)&Pw[wave][rbase ^ 16];

        // row-sum via ones-MFMA (lands in O-layout)
        accl = mfma16(pa0, ones, accl);
        accl = mfma16(pa1, ones, accl);

        #pragma unroll
        for (int dt = 0; dt < 4; ++dt) {
            short8 vf0 = *(const short8*)
                &Vsm[buf][(dt * 16 + l15) * 64 + (((0 + lg) ^ (l15 & 7)) * 8)];
            short8 vf1 = *(const short8*)
                &Vsm[buf][(dt * 16 + l15) * 64 + (((4 + lg) ^ (l15 & 7)) * 8)];
            o[dt] = mfma16(pa0, vf0, o[dt]);
            o[dt] = mfma16(pa1, vf1, o[dt]);
        }
    };

    stage(0, 0);
    for (int t = 0; t <= c; ++t) {
        const int cur = t & 1;
        __syncthreads();
        if (t < c) stage(cur ^ 1, t + 1);
        compute(cur, t);
    }

    // epilogue: O C-layout row(lg*4+j)=q-row, col(l15)=d.
    #pragma unroll
    for (int j = 0; j < 4; ++j) {
        const float inv_l = 1.0f / accl[j];
        const int s = q0 + lg * 4 + j;
        const int m = b * SEQ + s;
        #pragma unroll
        for (int dt = 0; dt < 4; ++dt) {
            const int col = h * 64 + dt * 16 + l15;
            const __hip_bfloat16 hv = __float2bfloat16(o[dt][j] * inv_l);
            if constexpr (TILED) {
                yp[(size_t)(col >> 5) * ((size_t)MROWS * 32)
                   + (size_t)m * 32 + (col & 31)] = hv;
            } else {
                yp[(size_t)m * CH + col] = hv;
            }
        }
    }
}

// ---------------------------------------------------------------------------
extern "C" void kernel_launch(void* const* d_in, const int* in_sizes, int n_in,
                              void* d_out, int out_size, void* d_ws, size_t ws_size,
                              hipStream_t stream)
{
    const float* x      = (const float*)d_in[0];
    const float* w_qkv  = (const float*)d_in[1];
    const float* w_proj = (const float*)d_in[2];
    float* out = (float*)d_out;

    __hip_bfloat16* ws = (__hip_bfloat16*)d_ws;

    if (ws_size >= 41943040ull) {
        __hip_bfloat16* xb   = ws;                     // K-tiled; dies after gemm1
        __hip_bfloat16* wqb  = ws + NX;                // K-tiled
        __hip_bfloat16* wpb  = ws + NX + NWQ;          // K-tiled
        __hip_bfloat16* q_ws = ws + NX + NWQ + NWP;
        __hip_bfloat16* k_ws = q_ws + (size_t)QSZ;
        __hip_bfloat16* vt_ws= k_ws + (size_t)QSZ;
        __hip_bfloat16* y_ws = xb;                     // K-tiled y (reuse xb slot)

        cvt3_kernel<<<(NX + NWQ + NWP) / 2048, 256, 0, stream>>>(
            x, w_qkv, w_proj, xb, wqb, wpb);

        gemm_w8<1><<<dim3(MROWS / 128, 3072 / 128), 512, 0, stream>>>(
            xb, wqb, CH, 3 * CH, nullptr, q_ws, k_ws, vt_ws);

        attn_fwd13<1><<<1024, 256, 0, stream>>>(q_ws, k_ws, vt_ws, y_ws);

        gemm_w8<0><<<dim3(MROWS / 128, CH / 128), 512, 0, stream>>>(
            y_ws, wpb, CH, CH, out, nullptr, nullptr, nullptr);
    } else {
        __hip_bfloat16* q_ws  = ws;
        __hip_bfloat16* k_ws  = ws + (size_t)QSZ;
        __hip_bfloat16* vt_ws = ws + (size_t)2 * QSZ;
        __hip_bfloat16* y_ws  = ws + (size_t)3 * QSZ;

        gemm_bt<1, float, float><<<dim3(MROWS / 128, 3072 / 128), 256, 0, stream>>>(
            x, w_qkv, CH, 3 * CH, nullptr, q_ws, k_ws, vt_ws);

        attn_fwd13<0><<<1024, 256, 0, stream>>>(q_ws, k_ws, vt_ws, y_ws);

        gemm_bt<0, __hip_bfloat16, float><<<dim3(MROWS / 128, CH / 128), 256, 0, stream>>>(
            y_ws, w_proj, CH, CH, out, nullptr, nullptr, nullptr);
    }
}